// Round 12
// baseline (40.705 us; speedup 1.0000x reference)
//
#include <hip/hip_runtime.h>
#include <math.h>

#define NH    16384   // Hadamard size (2^14)
#define NRES  8192
#define NINP  64
#define BATCH 512

typedef float v2f __attribute__((ext_vector_type(2)));

// ---------------- LDS swizzle ----------------------------------------------
// phys = idx ^ (g<<2), g = idx[5:7]^idx[8:10]^idx[11:13]. Both exchange
// layouts below give rank-3 lane->quadbank maps => conflict-free b128.
__device__ __forceinline__ constexpr int gfoldc(int v) {
    return ((v >> 5) & 7) ^ ((v >> 8) & 7) ^ ((v >> 11) & 7);
}
__device__ __forceinline__ constexpr int physf(int v) { return v ^ (gfoldc(v) << 2); }

// ---------------- packed butterfly primitives ------------------------------
__device__ __forceinline__ v2f pk_add(v2f a, v2f b) {
    v2f d; asm("v_pk_add_f32 %0, %1, %2" : "=v"(d) : "v"(a), "v"(b)); return d;
}
__device__ __forceinline__ v2f pk_sub(v2f a, v2f b, v2f n1) {
    v2f d; asm("v_pk_fma_f32 %0, %1, %2, %3" : "=v"(d) : "v"(b), "v"(n1), "v"(a)); return d;
}

// X[16] packs; element f (0..31) = X[f>>1][f&1]. idx0 = .x/.y, idx1 = pack
// bit0, j0..j2 = pack bits 1..3.
template <int T>
__device__ __forceinline__ void pstage(v2f X[16], v2f n1) {
#pragma unroll
    for (int p = 0; p < 16; ++p) if (!(p & T)) {
        v2f A = X[p], B = X[p | T];
        X[p]     = pk_add(A, B);
        X[p | T] = pk_sub(A, B, n1);
    }
}
__device__ __forceinline__ void vstage0(v2f X[16]) {
#pragma unroll
    for (int p = 0; p < 16; ++p) {
        float a = X[p].x, b = X[p].y;
        X[p].x = a + b; X[p].y = a - b;
    }
}
__device__ __forceinline__ void jpass(v2f X[16], v2f n1) {
    pstage<2>(X, n1); pstage<4>(X, n1); pstage<8>(X, n1);
}

// ---------------- cross-lane primitives ------------------------------------
template <int CTRL>
__device__ __forceinline__ float dppf(float v) {
    return __builtin_bit_cast(float,
        __builtin_amdgcn_update_dpp(0, __builtin_bit_cast(int, v), CTRL, 0xF, 0xF, true));
}
template <int CTRL>
__device__ __forceinline__ void dpp_swap(float A, float B, bool odd, float& oA, float& oB) {
    float dA = dppf<CTRL>(A), dB = dppf<CTRL>(B);
    oA = odd ? dB : A;
    oB = odd ? B  : dA;
}
__device__ __forceinline__ void pl16_swap(float& a, float& b) {
    asm("v_permlane16_swap_b32 %0, %1" : "+v"(a), "+v"(b));
}
__device__ __forceinline__ void pl32_swap(float& a, float& b) {
    asm("v_permlane32_swap_b32 %0, %1" : "+v"(a), "+v"(b));
}

// Shuffle-exchange (custody-relative, identical every time):
//  j0 (pack bit1) <-> l0 : DPP quad_perm xor1
//  j1 (pack bit2) <-> l4 : v_permlane16_swap_b32
//  j2 (pack bit3) <-> l5 : v_permlane32_swap_b32
__device__ __forceinline__ void shuffle_exchange(v2f X[16], bool odd0) {
#pragma unroll
    for (int p = 0; p < 16; ++p) if (!(p & 2)) {
        float a0, a1, b0, b1;
        dpp_swap<0xB1>(X[p].x, X[p | 2].x, odd0, a0, b0);
        dpp_swap<0xB1>(X[p].y, X[p | 2].y, odd0, a1, b1);
        X[p] = (v2f){a0, a1}; X[p | 2] = (v2f){b0, b1};
    }
#pragma unroll
    for (int p = 0; p < 16; ++p) if (!(p & 4)) {
        float a = X[p].x, b = X[p | 4].x; pl16_swap(a, b); X[p].x = a; X[p | 4].x = b;
        float c = X[p].y, d = X[p | 4].y; pl16_swap(c, d); X[p].y = c; X[p | 4].y = d;
    }
#pragma unroll
    for (int p = 0; p < 16; ++p) if (!(p & 8)) {
        float a = X[p].x, b = X[p | 8].x; pl32_swap(a, b); X[p].x = a; X[p | 8].x = b;
        float c = X[p].y, d = X[p | 8].y; pl32_swap(c, d); X[p].y = c; X[p | 8].y = d;
    }
}

// LDS-only barrier (no vmcnt drain: diag prefetches stay in flight)
#define BAR() asm volatile("s_waitcnt lgkmcnt(0)\n\ts_barrier" ::: "memory")

// Fast erf: erf(z) ~ tanh(z*(1.1283793 + 0.10090*z^2)), max err ~1e-3.
__device__ __forceinline__ float erf_fast(float z) {
    float p = z * z;
    float u = z * fmaf(p, 0.10090f, 1.1283793f);
    float e = __builtin_amdgcn_exp2f(u * 2.8853902f);
    float r = __builtin_amdgcn_rcpf(e + 1.0f);
    return fmaf(-2.0f, r, 1.0f);
}

// ---------------------------------------------------------------------------
// Periodic custody schedule, 512 threads (t = w<<6 | l), 16 v2f packs.
// Slots: v=idx{0,1}; j=pack bits1-3; s=(l0,l4,l5); f=(l1,l2,l3); w=(w0,w1,w2).
// Layer body: DIAG; v; pA(j); SHUF(j<->s); pB(j); LDS(j<->f, s<->w); pC(j);
//             SHUF; pD(j).   Custody states alternate:
//  State0 (layers 0,2 start): j=(2,3,4) s=(5,6,7) f=(8,9,10) w=(11,12,13)
//  State1 (layer 1 start):    j=(11,12,13) s=(8,9,10) f=(5,6,7) w=(2,3,4)
// LDS layouts: P (even-layer write / odd-layer read): g->(32,64,128),
//   lanes: l0*4+l4*8+l5*16 + l1*256+l2*512+l3*1024 + w*2048..8192.
// R (even-layer read / odd-layer write): g->(256,512,1024),
//   lanes: w*4..16 + l1*32+l2*64+l3*128 + l0*2048+l4*4096+l5*8192.
// ---------------------------------------------------------------------------
__global__ __launch_bounds__(512, 2) void st_kernel(
    const float* __restrict__ state, const float* __restrict__ inputs,
    const float* __restrict__ bias,  const float* __restrict__ diag,
    float* __restrict__ out)
{
    __shared__ float4 lds4[NH / 4];
    const int t = threadIdx.x;   // 0..511
    const int r = blockIdx.x;    // 0..511
    const int l = t & 63, w = t >> 6;
    const int l0=l&1, l1=(l>>1)&1, l2=(l>>2)&1, l3=(l>>3)&1, l4=(l>>4)&1, l5=(l>>5)&1;
    const int w0=w&1, w1=(w>>1)&1, w2=(w>>2)&1;
    const bool odd0 = l0;

    // State0 element base (also prologue load base) and State1 base.
    const int b0 = l0*32 + l4*64 + l5*128 + l1*256 + l2*512 + l3*1024
                 + w0*2048 + w1*4096 + w2*8192;
    const int b1 = w0*4 + w1*8 + w2*16 + l1*32 + l2*64 + l3*128
                 + l0*256 + l4*512 + l5*1024;
    // LDS layout lane-bases
    const int bP = l0*4 + l4*8 + l5*16 + l1*256 + l2*512 + l3*1024
                 + w0*2048 + w1*4096 + w2*8192;
    const int bR = w0*4 + w1*8 + w2*16 + l1*32 + l2*64 + l3*128
                 + l0*2048 + l4*4096 + l5*8192;

    // Rotating per-layer parameters (even layers use P-write/R-read).
    int Qw = physf(bP), Qr = physf(bR);
    int GW0 = 36,  GW1 = 72,  GW2 = 144;    // physf(32,64,128)
    int GR0 = 260, GR1 = 520, GR2 = 1040;   // physf(256,512,1024)
    int dbN = b1, DN0 = 2048, DN1 = 4096, DN2 = 8192;  // next-layer diag (layer1)
    int dbO = b0, DO0 = 4,    DO1 = 8,    DO2 = 16;    // the alternate set

    const v2f n1 = (v2f){-1.0f, -1.0f};
    v2f X[16];
    float4 dv[8];

    // ---------- prologue: load X (State0: idx = b0 + {0..31}) ----------
    if (t < 256) {                        // w2=0 -> state half
        const float* srow = state + (size_t)r * NRES + b0;
#pragma unroll
        for (int g = 0; g < 8; ++g) {
            float4 v = *(const float4*)(srow + 4 * g);
            X[2*g]   = (v2f){0.9f * v.x, 0.9f * v.y};
            X[2*g+1] = (v2f){0.9f * v.z, 0.9f * v.w};
        }
    } else if (t < 258) {                 // b0 in {8192, 8224} -> inputs
        const float* irow = inputs + r * NINP + (b0 - 8192);
#pragma unroll
        for (int g = 0; g < 8; ++g) {
            float4 v = *(const float4*)(irow + 4 * g);
            X[2*g]   = (v2f){0.4f * v.x, 0.4f * v.y};
            X[2*g+1] = (v2f){0.4f * v.z, 0.4f * v.w};
        }
    } else {
#pragma unroll
        for (int p = 0; p < 16; ++p) X[p] = (v2f){0.f, 0.f};
    }
    // diag layer 0 (State0 layout, contiguous)
#pragma unroll
    for (int g = 0; g < 8; ++g) dv[g] = *(const float4*)(diag + b0 + 4 * g);
    // bias prefetch (epilogue layout = State1, g<4)
    float4 bv[4];
#pragma unroll
    for (int g = 0; g < 4; ++g)
        bv[g] = *(const float4*)(bias + b1 + (g & 1) * 2048 + (g >> 1) * 4096);

    // ---------- 3 layers, one shared body ----------
#pragma unroll 1
    for (int lay = 0; lay < 3; ++lay) {
        // apply this layer's diag (prefetched)
#pragma unroll
        for (int g = 0; g < 8; ++g) {
            X[2*g]   *= (v2f){dv[g].x, dv[g].y};
            X[2*g+1] *= (v2f){dv[g].z, dv[g].w};
        }
        // prefetch next layer's diag (clamped on last iter; values unused)
        {
            const float* dn = diag + (size_t)((lay < 2) ? (lay + 1) : 2) * NH + dbN;
#pragma unroll
            for (int g = 0; g < 8; ++g) {
                const int off = ((g & 1) ? DN0 : 0) + ((g & 2) ? DN1 : 0) + ((g & 4) ? DN2 : 0);
                dv[g] = *(const float4*)(dn + off);
            }
        }
        vstage0(X); pstage<1>(X, n1);     // idx bits 0,1
        jpass(X, n1);                      // pA
        shuffle_exchange(X, odd0);         // j <-> s
        jpass(X, n1);                      // pB
        BAR();                             // previous reads done
#pragma unroll
        for (int g = 0; g < 8; ++g) {      // LDS write
            const int a = Qw ^ ((g & 1) ? GW0 : 0) ^ ((g & 2) ? GW1 : 0) ^ ((g & 4) ? GW2 : 0);
            lds4[(unsigned)a >> 2] =
                make_float4(X[2*g].x, X[2*g].y, X[2*g+1].x, X[2*g+1].y);
        }
        BAR();
#pragma unroll
        for (int g = 0; g < 8; ++g) {      // LDS read (j<->f, s<->w)
            const int a = Qr ^ ((g & 1) ? GR0 : 0) ^ ((g & 2) ? GR1 : 0) ^ ((g & 4) ? GR2 : 0);
            float4 v = lds4[(unsigned)a >> 2];
            X[2*g]   = (v2f){v.x, v.y};
            X[2*g+1] = (v2f){v.z, v.w};
        }
        jpass(X, n1);                      // pC
        shuffle_exchange(X, odd0);         // j <-> s
        jpass(X, n1);                      // pD
        // rotate per-layer parameters (custody states alternate)
        { int q = Qw; Qw = Qr; Qr = q; }
        { int a = GW0; GW0 = GR0; GR0 = a;
          int b = GW1; GW1 = GR1; GR1 = b;
          int c = GW2; GW2 = GR2; GR2 = c; }
        { int a = dbN; dbN = dbO; dbO = a;
          int x = DN0; DN0 = DO0; DO0 = x;
          int y = DN1; DN1 = DO1; DO1 = y;
          int z = DN2; DN2 = DO2; DO2 = z; }
    }

    // ---------- epilogue: custody State1 -> idx = b1 + g0*2048 + g1*4096 ----
    // idx13 = j2 = pack bit3 = 0 -> g < 4 (16 floats/thread, 512*16 = 8192)
    {
        float* orow = out + (size_t)r * NRES;
        const float inv = 1.0f / (float)NH;
#pragma unroll
        for (int g = 0; g < 4; ++g) {
            const int a = b1 + (g & 1) * 2048 + (g >> 1) * 4096;
            float4 o;
            o.x = erf_fast(fmaf(X[2*g].x,   inv, bv[g].x));
            o.y = erf_fast(fmaf(X[2*g].y,   inv, bv[g].y));
            o.z = erf_fast(fmaf(X[2*g+1].x, inv, bv[g].z));
            o.w = erf_fast(fmaf(X[2*g+1].y, inv, bv[g].w));
            *(float4*)(orow + a) = o;
        }
    }
}

extern "C" void kernel_launch(void* const* d_in, const int* in_sizes, int n_in,
                              void* d_out, int out_size, void* d_ws, size_t ws_size,
                              hipStream_t stream) {
    (void)in_sizes; (void)n_in; (void)out_size; (void)d_ws; (void)ws_size;
    const float* state  = (const float*)d_in[0];
    const float* inputs = (const float*)d_in[1];
    const float* bias   = (const float*)d_in[2];
    const float* diag   = (const float*)d_in[3];
    float* out = (float*)d_out;

    hipLaunchKernelGGL(st_kernel, dim3(BATCH), dim3(512), 0, stream,
                       state, inputs, bias, diag, out);
}

// Round 13
// 24.787 us; speedup vs baseline: 1.6422x; 1.6422x over previous
//
#include <hip/hip_runtime.h>
#include <math.h>

#define NH    16384   // Hadamard size (2^14)
#define NRES  8192
#define NINP  64
#define BATCH 512

typedef float v2f __attribute__((ext_vector_type(2)));

// ---------------- LDS swizzle ----------------------------------------------
// phys = idx ^ (gfold<<2), gfold = idx[5:7]^idx[8:10]^idx[11:13]. Bijective,
// float4-aligned. All 6 exchange layouts below verified rank-3 lane->quadbank
// (conflict-free b128).
__device__ __forceinline__ constexpr int gfoldc(int v) {
    return ((v >> 5) & 7) ^ ((v >> 8) & 7) ^ ((v >> 11) & 7);
}
__device__ __forceinline__ constexpr int physf(int v) { return v ^ (gfoldc(v) << 2); }

// ---------------- register butterflies (compiler packs v2f) ----------------
// X[32] packs; element f (0..63) = X[f>>1][f&1]. Pack bit0 = idx-custody v1,
// pack bits 1-4 = j0..j3.
template <int T>
__device__ __forceinline__ void pstage(v2f X[32]) {
#pragma unroll
    for (int p = 0; p < 32; ++p) if (!(p & T)) {
        v2f A = X[p], B = X[p | T];
        X[p]     = A + B;
        X[p | T] = A - B;
    }
}
__device__ __forceinline__ void vstage0(v2f X[32]) {
#pragma unroll
    for (int p = 0; p < 32; ++p) {
        float a = X[p].x, b = X[p].y;
        X[p].x = a + b; X[p].y = a - b;
    }
}

// ---------------- in-place lane butterflies (DPP) ---------------------------
template <int CTRL>
__device__ __forceinline__ float dppf(float v) {
    return __builtin_bit_cast(float,
        __builtin_amdgcn_update_dpp(0, __builtin_bit_cast(int, v), CTRL, 0xF, 0xF, true));
}
// Butterfly across a lane bit: x' = sgn*x + x[lane^k]; sgn = (lane&k)? -1:+1.
template <int CTRL>
__device__ __forceinline__ void dpp_bfly(v2f X[32], v2f sgn) {
#pragma unroll
    for (int p = 0; p < 32; ++p) {
        float y0 = dppf<CTRL>(X[p].x);
        float y1 = dppf<CTRL>(X[p].y);
        X[p] = sgn * X[p] + (v2f){y0, y1};
    }
}

// ---------------- permlane pair swaps (1 instr per reg-pair) ----------------
__device__ __forceinline__ void pl16_swap(float& a, float& b) {
    asm("v_permlane16_swap_b32 %0, %1" : "+v"(a), "+v"(b));
}
__device__ __forceinline__ void pl32_swap(float& a, float& b) {
    asm("v_permlane32_swap_b32 %0, %1" : "+v"(a), "+v"(b));
}
// swap pack-bit3 (pairs p,p|8) with lane-bit4
__device__ __forceinline__ void swap_j2_l4(v2f X[32]) {
#pragma unroll
    for (int p = 0; p < 32; ++p) if (!(p & 8)) {
        float a = X[p].x, b = X[p | 8].x; pl16_swap(a, b); X[p].x = a; X[p | 8].x = b;
        float c = X[p].y, d = X[p | 8].y; pl16_swap(c, d); X[p].y = c; X[p | 8].y = d;
    }
}
// swap pack-bit4 (pairs p,p|16) with lane-bit5
__device__ __forceinline__ void swap_j3_l5(v2f X[32]) {
#pragma unroll
    for (int p = 0; p < 32; ++p) if (!(p & 16)) {
        float a = X[p].x, b = X[p | 16].x; pl32_swap(a, b); X[p].x = a; X[p | 16].x = b;
        float c = X[p].y, d = X[p | 16].y; pl32_swap(c, d); X[p].y = c; X[p | 16].y = d;
    }
}

// ---------------- LDS exchange helpers --------------------------------------
#define GOFF4(g, G0, G1, G2, G3) \
    ((((g) & 1) ? (G0) : 0) | (((g) & 2) ? (G1) : 0) | \
     (((g) & 4) ? (G2) : 0) | (((g) & 8) ? (G3) : 0))

#define WRX(Q, G0, G1, G2, G3) do { _Pragma("unroll") \
    for (int g = 0; g < 16; ++g) { \
        const int a = (Q) ^ physf(GOFF4(g, G0, G1, G2, G3)); \
        lds4[(unsigned)a >> 2] = \
            make_float4(X[2*g].x, X[2*g].y, X[2*g+1].x, X[2*g+1].y); \
    } } while (0)

#define RDX(Q, G0, G1, G2, G3) do { _Pragma("unroll") \
    for (int g = 0; g < 16; ++g) { \
        const int a = (Q) ^ physf(GOFF4(g, G0, G1, G2, G3)); \
        float4 v = lds4[(unsigned)a >> 2]; \
        X[2*g]   = (v2f){v.x, v.y}; \
        X[2*g+1] = (v2f){v.z, v.w}; \
    } } while (0)

#define DIAG_LOAD(PF, BASE, G0, G1, G2, G3) do { _Pragma("unroll") \
    for (int g = 0; g < 16; ++g) \
        (PF)[g] = *(const float4*)((BASE) + GOFF4(g, G0, G1, G2, G3)); } while (0)

#define DIAG_APPLY(PF) do { _Pragma("unroll") \
    for (int g = 0; g < 16; ++g) { \
        X[2*g]   *= (v2f){(PF)[g].x, (PF)[g].y}; \
        X[2*g+1] *= (v2f){(PF)[g].z, (PF)[g].w}; \
    } } while (0)

// LDS-only barrier (global prefetches stay in flight)
#define BAR() asm volatile("s_waitcnt lgkmcnt(0)\n\ts_barrier" ::: "memory")

// Fast erf: erf(z) ~ tanh(z*(1.1283793 + 0.10090*z^2)), max err ~1e-3.
__device__ __forceinline__ float erf_fast(float z) {
    float p = z * z;
    float u = z * fmaf(p, 0.10090f, 1.1283793f);
    float e = __builtin_amdgcn_exp2f(u * 2.8853902f);
    float r = __builtin_amdgcn_rcpf(e + 1.0f);
    return fmaf(-2.0f, r, 1.0f);
}

// ---------------------------------------------------------------------------
// Custody plan (256 threads, 64 floats/thread). Slots: v={i0,i1} in-register;
// j0..j3 = pack bits 1-4; lanes l0..l5; waves w0,w1. Lane bits l0,l1 are
// butterflied IN PLACE via DPP (xor1/xor2) each layer; l4,l5 via permlane
// pair-swaps into j2,j3; l2,l3 + w0,w1 via the LDS relabel exchanges.
//
// L0 start (load layout, idx = t*64+f): v{0,1} j{2,3,4,5} l{6,7,8,9,4*,5*}
//   -- precisely: l0..l5 = i6..i11, w = i12,i13.
// L0: reg i0..i5; dpp i6,i7; plswap(j2<->l4: i4done<->i10, j3<->l5: i5<->i11);
//     reg i10,i11; LDS#1 relabel; reg i8,i9,i12,i13.
// post-#1 custody: j{8,9,12,13} l0l1{6,7} l2l3{2,3} l4l5{4,5} w{10,11}
// L1: diag1; reg i0,i1,i8,i9,i12,i13; dpp i6,i7; plswap (i12,i13 out; i4,i5 in);
//     reg i4,i5; LDS#2; reg i2,i3,i10,i11.
// post-#2: j{2,3,10,11} l0l1{6,7} l2l3{8,9} l4l5{12,13} w{4,5}
// L2: diag2; reg i0,i1,i2,i3,i10,i11; dpp i6,i7; plswap (i10,i11 out; i12,i13 in);
//     reg i12,i13; LDS#3; reg i4,i5,i8,i9.
// post-#3: j{4,5,8,9} l0=i2 l1=i3 l2=i6 l3=i7 l4=i10 l5=i13 w0=i11 w1=i12
// final plswap j3(i9)<->l5(i13): j={4,5,8,13} -> packs with bit4=0 are output.
// ---------------------------------------------------------------------------
__global__ __launch_bounds__(256, 2) void st_kernel(
    const float* __restrict__ state, const float* __restrict__ inputs,
    const float* __restrict__ bias,  const float* __restrict__ diag,
    float* __restrict__ out)
{
    __shared__ float4 lds4[NH / 4];
    const int t = threadIdx.x;   // 0..255
    const int r = blockIdx.x;    // 0..511
    const int l = t & 63, w = t >> 6;
    const int l0=l&1, l1=(l>>1)&1, l2=(l>>2)&1, l3=(l>>3)&1, l4=(l>>4)&1, l5=(l>>5)&1;
    const int w0=w&1, w1=(w>>1)&1;

    const v2f s1 = (v2f){l0 ? -1.f : 1.f, l0 ? -1.f : 1.f};
    const v2f s2 = (v2f){l1 ? -1.f : 1.f, l1 ? -1.f : 1.f};

    // idx-space bases for the LDS layouts / diag / store (custody tables above)
    const int b_w1 = l0*64 + l1*128 + l2*256 + l3*512 + l4*16  + l5*32
                   + w0*4096 + w1*8192;
    const int b_r1 = l0*64 + l1*128 + l2*4   + l3*8   + l4*16  + l5*32
                   + w0*1024 + w1*2048;
    const int b_w2 = l0*64 + l1*128 + l2*4   + l3*8   + l4*4096 + l5*8192
                   + w0*1024 + w1*2048;
    const int b_r2 = l0*64 + l1*128 + l2*256 + l3*512 + l4*4096 + l5*8192
                   + w0*16 + w1*32;
    const int b_w3 = l0*64 + l1*128 + l2*256 + l3*512 + l4*1024 + l5*2048
                   + w0*16 + w1*32;
    const int b_r3 = l0*4  + l1*8   + l2*64  + l3*128 + l4*1024 + l5*8192
                   + w0*2048 + w1*4096;
    const int b_st = l0*4  + l1*8   + l2*64  + l3*128 + l4*1024 + l5*512
                   + w0*2048 + w1*4096;

    v2f X[32];
    float4 pf[16];

    // ---------- prologue: load + diag0 (layout idx = t*64 + f) ----------
    if (t < 128) {
        const float* srow = state + (size_t)r * NRES + t * 64;
        const float* d0   = diag + t * 64;
#pragma unroll
        for (int g = 0; g < 16; ++g) {
            float4 v = *(const float4*)(srow + 4 * g);
            float4 d = *(const float4*)(d0 + 4 * g);
            X[2*g]   = (v2f){0.9f * v.x * d.x, 0.9f * v.y * d.y};
            X[2*g+1] = (v2f){0.9f * v.z * d.z, 0.9f * v.w * d.w};
        }
    } else if (t == 128) {
        const float* irow = inputs + r * NINP;
        const float* d0   = diag + NRES;
#pragma unroll
        for (int g = 0; g < 16; ++g) {
            float4 v = *(const float4*)(irow + 4 * g);
            float4 d = *(const float4*)(d0 + 4 * g);
            X[2*g]   = (v2f){0.4f * v.x * d.x, 0.4f * v.y * d.y};
            X[2*g+1] = (v2f){0.4f * v.z * d.z, 0.4f * v.w * d.w};
        }
    } else {
#pragma unroll
        for (int p = 0; p < 32; ++p) X[p] = (v2f){0.f, 0.f};
    }

    // ================= layer 0 =================
    vstage0(X); pstage<1>(X);                    // i0, i1
    pstage<2>(X); pstage<4>(X); pstage<8>(X); pstage<16>(X);   // i2..i5
    dpp_bfly<0xB1>(X, s1);                       // i6 (lane xor1)
    dpp_bfly<0x4E>(X, s2);                       // i7 (lane xor2)
    swap_j2_l4(X); swap_j3_l5(X);                // j2<-i10, j3<-i11
    pstage<8>(X); pstage<16>(X);                 // i10, i11

    // diag1 prefetch (post-#1 custody layout) -- issued before the exchange
    DIAG_LOAD(pf, diag + NH + b_r1, 256, 512, 4096, 8192);

    // LDS #1: relabel
    { const int Q = physf(b_w1); WRX(Q, 4, 8, 1024, 2048); }
    BAR();
    { const int Q = physf(b_r1); RDX(Q, 256, 512, 4096, 8192); }
    pstage<2>(X); pstage<4>(X); pstage<8>(X); pstage<16>(X);   // i8,i9,i12,i13

    // ================= layer 1 =================
    DIAG_APPLY(pf);                              // diag1
    vstage0(X); pstage<1>(X);                    // i0, i1
    pstage<2>(X); pstage<4>(X); pstage<8>(X); pstage<16>(X);   // i8,i9,i12,i13
    dpp_bfly<0xB1>(X, s1);                       // i6
    dpp_bfly<0x4E>(X, s2);                       // i7
    swap_j2_l4(X); swap_j3_l5(X);                // j2<-i4, j3<-i5
    pstage<8>(X); pstage<16>(X);                 // i4, i5

    // diag2 prefetch (post-#2 custody layout)
    DIAG_LOAD(pf, diag + 2 * NH + b_r2, 4, 8, 1024, 2048);

    // LDS #2
    BAR();                                       // protect #1 reads
    { const int Q = physf(b_w2); WRX(Q, 256, 512, 16, 32); }
    BAR();
    { const int Q = physf(b_r2); RDX(Q, 4, 8, 1024, 2048); }
    pstage<2>(X); pstage<4>(X); pstage<8>(X); pstage<16>(X);   // i2,i3,i10,i11

    // ================= layer 2 =================
    DIAG_APPLY(pf);                              // diag2
    vstage0(X); pstage<1>(X);                    // i0, i1
    pstage<2>(X); pstage<4>(X); pstage<8>(X); pstage<16>(X);   // i2,i3,i10,i11
    dpp_bfly<0xB1>(X, s1);                       // i6
    dpp_bfly<0x4E>(X, s2);                       // i7
    swap_j2_l4(X); swap_j3_l5(X);                // j2<-i12, j3<-i13
    pstage<8>(X); pstage<16>(X);                 // i12, i13

    // bias prefetch (store layout, 8 float4)
    float4 bv[8];
#pragma unroll
    for (int g = 0; g < 8; ++g)
        bv[g] = *(const float4*)(bias + b_st + GOFF4(g, 16, 32, 256, 0));

    // LDS #3
    BAR();                                       // protect #2 reads
    { const int Q = physf(b_w3); WRX(Q, 4, 8, 4096, 8192); }
    BAR();
    { const int Q = physf(b_r3); RDX(Q, 16, 32, 256, 512); }
    pstage<2>(X); pstage<4>(X); pstage<8>(X); pstage<16>(X);   // i4,i5,i8,i9

    // bring i13 into pack bit4 (j3<->l5) so every thread stores 8 float4s
    swap_j3_l5(X);

    // ---------- epilogue: packs with bit4=0 -> idx13=0 ----------
    {
        float* orow = out + (size_t)r * NRES;
        const float inv = 1.0f / (float)NH;
#pragma unroll
        for (int g = 0; g < 8; ++g) {
            const int a = b_st + GOFF4(g, 16, 32, 256, 0);
            float4 o;
            o.x = erf_fast(fmaf(X[2*g].x,   inv, bv[g].x));
            o.y = erf_fast(fmaf(X[2*g].y,   inv, bv[g].y));
            o.z = erf_fast(fmaf(X[2*g+1].x, inv, bv[g].z));
            o.w = erf_fast(fmaf(X[2*g+1].y, inv, bv[g].w));
            *(float4*)(orow + a) = o;
        }
    }
}

extern "C" void kernel_launch(void* const* d_in, const int* in_sizes, int n_in,
                              void* d_out, int out_size, void* d_ws, size_t ws_size,
                              hipStream_t stream) {
    (void)in_sizes; (void)n_in; (void)out_size; (void)d_ws; (void)ws_size;
    const float* state  = (const float*)d_in[0];
    const float* inputs = (const float*)d_in[1];
    const float* bias   = (const float*)d_in[2];
    const float* diag   = (const float*)d_in[3];
    float* out = (float*)d_out;

    hipLaunchKernelGGL(st_kernel, dim3(BATCH), dim3(256), 0, stream,
                       state, inputs, bias, diag, out);
}

// Round 14
// 23.599 us; speedup vs baseline: 1.7249x; 1.0503x over previous
//
#include <hip/hip_runtime.h>
#include <math.h>

#define NH    16384   // Hadamard size (2^14)
#define NRES  8192
#define NINP  64
#define BATCH 512

typedef float v2f __attribute__((ext_vector_type(2)));

// ---------------- LDS swizzle ----------------------------------------------
// phys = idx ^ (gfold<<2), gfold = idx[5:7]^idx[8:10]^idx[11:13]. Bijective,
// float4-aligned. All 6 exchange layouts verified rank-3 lane->quadbank:
//  EX1-W (l2^l5, l0^l3, l1^l4)  EX1-R/EX3-R (l0^l5, l1^l2, l3^l4)
//  EX2-W (l0, l1^l2^l4, l3^l5)  EX2-R (l0^l2^l5, l1^l3, l4)
//  EX3-W (l0^l2^l5, l1^l3, l4)
__device__ __forceinline__ constexpr int gfoldc(int v) {
    return ((v >> 5) & 7) ^ ((v >> 8) & 7) ^ ((v >> 11) & 7);
}
__device__ __forceinline__ constexpr int physf(int v) { return v ^ (gfoldc(v) << 2); }

// ---------------- register butterflies (compiler packs v2f) ----------------
// X[32] packs; element f (0..63) = X[f>>1][f&1]. Element bit0 = idx0 custody,
// pack bit0 = idx1 custody, pack bits 1-4 = j0..j3.
template <int T>
__device__ __forceinline__ void pstage(v2f X[32]) {
#pragma unroll
    for (int p = 0; p < 32; ++p) if (!(p & T)) {
        v2f A = X[p], B = X[p | T];
        X[p]     = A + B;
        X[p | T] = A - B;
    }
}
__device__ __forceinline__ void vstage0(v2f X[32]) {
#pragma unroll
    for (int p = 0; p < 32; ++p) {
        float a = X[p].x, b = X[p].y;
        X[p].x = a + b; X[p].y = a - b;
    }
}

// ---------------- in-place lane butterflies (DPP) ---------------------------
template <int CTRL>
__device__ __forceinline__ float dppf(float v) {
    return __builtin_bit_cast(float,
        __builtin_amdgcn_update_dpp(0, __builtin_bit_cast(int, v), CTRL, 0xF, 0xF, true));
}
// x' = sgn*x + x[lane^k]; sgn = (lane&k) ? -1 : +1.
template <int CTRL>
__device__ __forceinline__ void dpp_bfly(v2f X[32], v2f sgn) {
#pragma unroll
    for (int p = 0; p < 32; ++p) {
        float y0 = dppf<CTRL>(X[p].x);
        float y1 = dppf<CTRL>(X[p].y);
        X[p] = sgn * X[p] + (v2f){y0, y1};
    }
}

// ---------------- permlane pair swaps (1 instr per reg-pair) ----------------
__device__ __forceinline__ void pl16_swap(float& a, float& b) {
    asm("v_permlane16_swap_b32 %0, %1" : "+v"(a), "+v"(b));
}
__device__ __forceinline__ void pl32_swap(float& a, float& b) {
    asm("v_permlane32_swap_b32 %0, %1" : "+v"(a), "+v"(b));
}
// swap custody of pack-bit3 (pairs p,p|8) with lane-bit4
__device__ __forceinline__ void swap_j2_l4(v2f X[32]) {
#pragma unroll
    for (int p = 0; p < 32; ++p) if (!(p & 8)) {
        float a = X[p].x, b = X[p | 8].x; pl16_swap(a, b); X[p].x = a; X[p | 8].x = b;
        float c = X[p].y, d = X[p | 8].y; pl16_swap(c, d); X[p].y = c; X[p | 8].y = d;
    }
}
// swap custody of pack-bit4 (pairs p,p|16) with lane-bit5
__device__ __forceinline__ void swap_j3_l5(v2f X[32]) {
#pragma unroll
    for (int p = 0; p < 32; ++p) if (!(p & 16)) {
        float a = X[p].x, b = X[p | 16].x; pl32_swap(a, b); X[p].x = a; X[p | 16].x = b;
        float c = X[p].y, d = X[p | 16].y; pl32_swap(c, d); X[p].y = c; X[p | 16].y = d;
    }
}

// ---------------- LDS / global helpers --------------------------------------
#define GOFF4(g, G0, G1, G2, G3) \
    ((((g) & 1) ? (G0) : 0) | (((g) & 2) ? (G1) : 0) | \
     (((g) & 4) ? (G2) : 0) | (((g) & 8) ? (G3) : 0))

#define WRX(Q, G0, G1, G2, G3) do { _Pragma("unroll") \
    for (int g = 0; g < 16; ++g) { \
        const int a = (Q) ^ physf(GOFF4(g, G0, G1, G2, G3)); \
        lds4[(unsigned)a >> 2] = \
            make_float4(X[2*g].x, X[2*g].y, X[2*g+1].x, X[2*g+1].y); \
    } } while (0)

#define RDX(Q, G0, G1, G2, G3) do { _Pragma("unroll") \
    for (int g = 0; g < 16; ++g) { \
        const int a = (Q) ^ physf(GOFF4(g, G0, G1, G2, G3)); \
        float4 v = lds4[(unsigned)a >> 2]; \
        X[2*g]   = (v2f){v.x, v.y}; \
        X[2*g+1] = (v2f){v.z, v.w}; \
    } } while (0)

#define DIAG_LOAD(PF, BASE, G0, G1, G2, G3) do { _Pragma("unroll") \
    for (int g = 0; g < 16; ++g) \
        (PF)[g] = *(const float4*)((BASE) + GOFF4(g, G0, G1, G2, G3)); } while (0)

#define DIAG_APPLY(PF) do { _Pragma("unroll") \
    for (int g = 0; g < 16; ++g) { \
        X[2*g]   *= (v2f){(PF)[g].x, (PF)[g].y}; \
        X[2*g+1] *= (v2f){(PF)[g].z, (PF)[g].w}; \
    } } while (0)

// LDS-only barrier (global prefetches stay in flight)
#define BAR() asm volatile("s_waitcnt lgkmcnt(0)\n\ts_barrier" ::: "memory")

// Fast erf: erf(z) ~ tanh(z*(1.1283793 + 0.10090*z^2)), max err ~1e-3.
__device__ __forceinline__ float erf_fast(float z) {
    float p = z * z;
    float u = z * fmaf(p, 0.10090f, 1.1283793f);
    float e = __builtin_amdgcn_exp2f(u * 2.8853902f);
    float r = __builtin_amdgcn_rcpf(e + 1.0f);
    return fmaf(-2.0f, r, 1.0f);
}

// ---------------------------------------------------------------------------
// Coalesced-custody plan (256 threads, 64 floats/thread).
// Load custody (natural): v{0,1} j{2,3,4,5} l{6,7,8,9,10,11} w{12,13}.
// L0: v; j(2,3,4,5); dpp(6,7); plswap -> j2,j3 pick up 10,11 -> bfly(10,11).
//   EX1-W: j{2,3,10,11} l{6,7,8,9,4,5} w{12,13}
//   EX1-R: j{8,9,12,13} l{2,3,6,7,4,5} w{10,11}   <- diag1 HERE: lanes=bits2-7
//   post: bfly(8,9,12,13) completes L0.
// L1: diag1; v; j(8,9,12,13); dpp(2,3); plswap -> bfly(4,5).
//   EX2-W: j{8,9,4,5} l{2,3,6,7,12,13} w{10,11}
//   EX2-R: j{6,7,10,11} l{2,3,8,9,4,5} w{12,13}   <- diag2: lanes=2-5 + 8,9
//   post: bfly(6,7,10,11) completes L1.
// L2: diag2; v; j(6,7,10,11); dpp(2,3); plswap -> bfly(4,5).
//   EX3-W: j{6,7,4,5} l{2,3,8,9,10,11} w{12,13}
//   EX3-R = EX1-R layout: j{8,9,12,13} l{2,3,6,7,4,5} w{10,11}
//   post: bfly(8,9,12,13) completes L2.
// Store: idx13 = j3 -> g<8; addr lanes = bits 2-7 -> contiguous 1KB/instr.
// ---------------------------------------------------------------------------
__global__ __launch_bounds__(256, 2) void st_kernel(
    const float* __restrict__ state, const float* __restrict__ inputs,
    const float* __restrict__ bias,  const float* __restrict__ diag,
    float* __restrict__ out)
{
    __shared__ float4 lds4[NH / 4];
    const int t = threadIdx.x;   // 0..255
    const int r = blockIdx.x;    // 0..511
    const int l = t & 63, w = t >> 6;
    const int l0=l&1, l1=(l>>1)&1, l2=(l>>2)&1, l3=(l>>3)&1, l4=(l>>4)&1, l5=(l>>5)&1;
    const int w0=w&1, w1=(w>>1)&1;

    const v2f s1 = (v2f){l0 ? -1.f : 1.f, l0 ? -1.f : 1.f};
    const v2f s2 = (v2f){l1 ? -1.f : 1.f, l1 ? -1.f : 1.f};

    // idx-space thread bases (float units) per custody tables above
    const int b_w1 = l0*64 + l1*128 + l2*256 + l3*512 + l4*16 + l5*32
                   + w0*4096 + w1*8192;
    const int b_r1 = l0*4 + l1*8 + l2*64 + l3*128 + l4*16 + l5*32
                   + w0*1024 + w1*2048;
    const int b_w2 = l0*4 + l1*8 + l2*64 + l3*128 + l4*4096 + l5*8192
                   + w0*1024 + w1*2048;
    const int b_r2 = l0*4 + l1*8 + l2*256 + l3*512 + l4*16 + l5*32
                   + w0*4096 + w1*8192;
    const int b_w3 = l0*4 + l1*8 + l2*256 + l3*512 + l4*1024 + l5*2048
                   + w0*4096 + w1*8192;

    v2f X[32];
    float4 pf[16];

    // ---------- prologue: load + diag0 (natural layout idx = t*64 + f) ------
    if (t < 128) {
        const float* srow = state + (size_t)r * NRES + t * 64;
        const float* d0   = diag + t * 64;
#pragma unroll
        for (int g = 0; g < 16; ++g) {
            float4 v = *(const float4*)(srow + 4 * g);
            float4 d = *(const float4*)(d0 + 4 * g);
            X[2*g]   = (v2f){0.9f * v.x * d.x, 0.9f * v.y * d.y};
            X[2*g+1] = (v2f){0.9f * v.z * d.z, 0.9f * v.w * d.w};
        }
    } else if (t == 128) {
        const float* irow = inputs + r * NINP;
        const float* d0   = diag + NRES;
#pragma unroll
        for (int g = 0; g < 16; ++g) {
            float4 v = *(const float4*)(irow + 4 * g);
            float4 d = *(const float4*)(d0 + 4 * g);
            X[2*g]   = (v2f){0.4f * v.x * d.x, 0.4f * v.y * d.y};
            X[2*g+1] = (v2f){0.4f * v.z * d.z, 0.4f * v.w * d.w};
        }
    } else {
#pragma unroll
        for (int p = 0; p < 32; ++p) X[p] = (v2f){0.f, 0.f};
    }

    // ================= layer 0 =================
    vstage0(X); pstage<1>(X);                       // idx 0,1
    pstage<2>(X); pstage<4>(X); pstage<8>(X); pstage<16>(X);   // idx 2,3,4,5
    dpp_bfly<0xB1>(X, s1);                          // idx 6 (l0)
    dpp_bfly<0x4E>(X, s2);                          // idx 7 (l1)
    swap_j2_l4(X); swap_j3_l5(X);                   // j2<-10, j3<-11 (4,5 -> lanes)
    pstage<8>(X); pstage<16>(X);                    // idx 10, 11

    // diag1 prefetch (EX1-R custody: coalesced 1KB/instr)
    DIAG_LOAD(pf, diag + NH + b_r1, 256, 512, 4096, 8192);

    // EX1
    { const int Q = physf(b_w1); WRX(Q, 4, 8, 1024, 2048); }
    BAR();
    { const int Q = physf(b_r1); RDX(Q, 256, 512, 4096, 8192); }
    pstage<2>(X); pstage<4>(X); pstage<8>(X); pstage<16>(X);   // idx 8,9,12,13

    // ================= layer 1 =================
    DIAG_APPLY(pf);                                 // diag1
    vstage0(X); pstage<1>(X);                       // idx 0,1
    pstage<2>(X); pstage<4>(X); pstage<8>(X); pstage<16>(X);   // idx 8,9,12,13
    dpp_bfly<0xB1>(X, s1);                          // idx 2
    dpp_bfly<0x4E>(X, s2);                          // idx 3
    swap_j2_l4(X); swap_j3_l5(X);                   // j2<-4, j3<-5 (12,13 -> lanes)
    pstage<8>(X); pstage<16>(X);                    // idx 4, 5

    // diag2 prefetch (EX2-R custody: 4x256B full-line segments/instr)
    DIAG_LOAD(pf, diag + 2 * NH + b_r2, 64, 128, 1024, 2048);

    // EX2
    BAR();                                          // protect EX1 reads
    { const int Q = physf(b_w2); WRX(Q, 256, 512, 16, 32); }
    BAR();
    { const int Q = physf(b_r2); RDX(Q, 64, 128, 1024, 2048); }
    pstage<2>(X); pstage<4>(X); pstage<8>(X); pstage<16>(X);   // idx 6,7,10,11

    // ================= layer 2 =================
    DIAG_APPLY(pf);                                 // diag2
    vstage0(X); pstage<1>(X);                       // idx 0,1
    pstage<2>(X); pstage<4>(X); pstage<8>(X); pstage<16>(X);   // idx 6,7,10,11
    dpp_bfly<0xB1>(X, s1);                          // idx 2
    dpp_bfly<0x4E>(X, s2);                          // idx 3
    swap_j2_l4(X); swap_j3_l5(X);                   // j2<-4, j3<-5 (10,11 -> lanes)
    pstage<8>(X); pstage<16>(X);                    // idx 4, 5

    // bias prefetch (store custody = EX1-R layout, g<8: coalesced 1KB/instr)
    float4 bv[8];
#pragma unroll
    for (int g = 0; g < 8; ++g)
        bv[g] = *(const float4*)(bias + b_r1 + GOFF4(g, 256, 512, 4096, 0));

    // EX3
    BAR();                                          // protect EX2 reads
    { const int Q = physf(b_w3); WRX(Q, 64, 128, 16, 32); }
    BAR();
    { const int Q = physf(b_r1); RDX(Q, 256, 512, 4096, 8192); }
    pstage<2>(X); pstage<4>(X); pstage<8>(X); pstage<16>(X);   // idx 8,9,12,13

    // ---------- epilogue: idx13 = j3 -> packs with bit4=0 (g<8) ----------
    {
        float* orow = out + (size_t)r * NRES;
        const float inv = 1.0f / (float)NH;
#pragma unroll
        for (int g = 0; g < 8; ++g) {
            const int a = b_r1 + GOFF4(g, 256, 512, 4096, 0);
            float4 o;
            o.x = erf_fast(fmaf(X[2*g].x,   inv, bv[g].x));
            o.y = erf_fast(fmaf(X[2*g].y,   inv, bv[g].y));
            o.z = erf_fast(fmaf(X[2*g+1].x, inv, bv[g].z));
            o.w = erf_fast(fmaf(X[2*g+1].y, inv, bv[g].w));
            *(float4*)(orow + a) = o;
        }
    }
}

extern "C" void kernel_launch(void* const* d_in, const int* in_sizes, int n_in,
                              void* d_out, int out_size, void* d_ws, size_t ws_size,
                              hipStream_t stream) {
    (void)in_sizes; (void)n_in; (void)out_size; (void)d_ws; (void)ws_size;
    const float* state  = (const float*)d_in[0];
    const float* inputs = (const float*)d_in[1];
    const float* bias   = (const float*)d_in[2];
    const float* diag   = (const float*)d_in[3];
    float* out = (float*)d_out;

    hipLaunchKernelGGL(st_kernel, dim3(BATCH), dim3(256), 0, stream,
                       state, inputs, bias, diag, out);
}